// Round 10
// baseline (1036.200 us; speedup 1.0000x reference)
//
#include <hip/hip_runtime.h>
#include <hip/hip_bf16.h>

#define NN      2048
#define NSTEPS  2047
#define NPAIRS  1024
#define MROWS   8192

typedef __attribute__((ext_vector_type(8))) __bf16 bf16x8;
typedef __attribute__((ext_vector_type(4))) float  f32x4;
typedef __attribute__((ext_vector_type(2))) float  f32x2;

__device__ __forceinline__ unsigned short f2bf(float f) {
  unsigned int u = __float_as_uint(f);
  u += 0x7fffu + ((u >> 16) & 1u);   // RNE
  return (unsigned short)(u >> 16);
}

__device__ __forceinline__ void gload_lds16(const void* g, void* l) {
  __builtin_amdgcn_global_load_lds((const __attribute__((address_space(1))) void*)g,
                                   (__attribute__((address_space(3))) void*)l, 16, 0, 0);
}

// DPP wave-wide lane shifts (VALU pipe, no LDS). Verified rounds 6-9.
template<int CTRL>
__device__ __forceinline__ float dppf(float v) {
  return __int_as_float(__builtin_amdgcn_update_dpp(
      __float_as_int(v), __float_as_int(v), CTRL, 0xf, 0xf, false));
}
#define DPP_UP 0x138   // wave_shr1: dst[i] = src[i-1]  (shfl_up 1)
#define DPP_DN 0x130   // wave_shl1: dst[i] = src[i+1]  (shfl_down 1)

// Packed fp32 math with op_sel broadcast from a (c,s) register pair. Verified rounds 7-9.
__device__ __forceinline__ f32x2 pk_smul(f32x2 cs, f32x2 v) {
  f32x2 d;
  asm("v_pk_mul_f32 %0, %1, %2 op_sel:[1,0] op_sel_hi:[1,1]"
      : "=v"(d) : "v"(cs), "v"(v));
  return d;
}
__device__ __forceinline__ f32x2 pk_cfma(f32x2 cs, f32x2 v, f32x2 a) {
  f32x2 d;
  asm("v_pk_fma_f32 %0, %1, %2, %3 op_sel:[0,0,0] op_sel_hi:[0,1,1]"
      : "=v"(d) : "v"(cs), "v"(v), "v"(a));
  return d;
}
__device__ __forceinline__ f32x2 pk_cfma_neg(f32x2 cs, f32x2 v, f32x2 a) {
  f32x2 d;
  asm("v_pk_fma_f32 %0, %1, %2, %3 op_sel:[0,0,0] op_sel_hi:[0,1,1] neg_lo:[0,0,1] neg_hi:[0,0,1]"
      : "=v"(d) : "v"(cs), "v"(v), "v"(a));
  return d;
}

// ---- kernel 1: angles -> (cos,sin) table, layout cs[step][pair] (8 KB/step slice)
__global__ __launch_bounds__(256) void prep_kernel(
    const float* __restrict__ angles, float2* __restrict__ cs) {
  int idx = blockIdx.x * 256 + threadIdx.x;
  if (idx >= NSTEPS * NPAIRS) return;
  float s, c;
  sincosf(angles[idx], &s, &c);
  cs[idx] = make_float2(c, s);
}

// ---- kernel 2: x fp32 -> bf16 (vectorized)
__global__ __launch_bounds__(256) void cvt_kernel(
    const float4* __restrict__ x, ushort4* __restrict__ xb, int n4) {
  int idx = blockIdx.x * 256 + threadIdx.x;
  if (idx >= n4) return;
  float4 v = x[idx];
  ushort4 o;
  o.x = f2bf(v.x); o.y = f2bf(v.y); o.z = f2bf(v.z); o.w = f2bf(v.w);
  xb[idx] = o;
}

// ---- kernel 3: register-systolic build of U (position space, static pairing).
// Round-3 geometry (verified): WG = 2 waves (h = pair-half); wave h owns pairs
// p = 512h + 8*lane + e (e=0..7) for ONE row-pair (rows 2b, 2b+1 as f32x2).
// 1024 WGs x 2 waves = 2048 waves = 2/SIMD; 4 WGs/CU share each cs slice via L1.
// pk-asm rotations + DPP shifts + direct global->reg cs (E/O buffers, 2 ahead).
// Reg map at step T (PHI=T&7): F elem e <-> FF[(e-T)&7], S elem e <-> SS[(e+T)&7].
__global__ __launch_bounds__(128, 2) void build_kernel(
    const char* __restrict__ csb, unsigned short* __restrict__ Ub) {
  __shared__ f32x2 exF[2], exS[2];   // [step parity]; F: h0.l63 -> h1.l0; S: h1.l0 -> h0.l63

  const int tid  = threadIdx.x;
  const int lane = tid & 63;
  const int h    = tid >> 6;               // pair-half 0/1
  const int r0   = blockIdx.x * 2;         // rows r0, r0+1
  const bool l0 = (lane == 0), l63 = (lane == 63);
  const bool h1 = (h == 1);

  // state: elem e <-> pair p = 512h + 8*lane + e; .x = row r0, .y = row r0+1
  f32x2 FF[8], SS[8];
#pragma unroll
  for (int e = 0; e < 8; ++e) {
    const int p = 512 * h + 8 * lane + e, m = 2047 - p;
    FF[e] = (f32x2){(p == r0) ? 1.f : 0.f, (p == r0 + 1) ? 1.f : 0.f};
    SS[e] = (f32x2){(m == r0) ? 1.f : 0.f, (m == r0 + 1) ? 1.f : 0.f};
  }

  // cs: lane's 8 pairs = 64B contiguous at slice_base + 4096h + 64*lane.
  // E/O slice double-buffer, each prefetched 2 slices ahead (round-8/9 scheme).
  const char* gpE = csb + 4096 * h + 64 * lane;   // even slices
  const char* gpO = gpE + 8192;                   // odd slices
  float4 cE0 = ((const float4*)gpE)[0], cE1 = ((const float4*)gpE)[1];
  float4 cE2 = ((const float4*)gpE)[2], cE3 = ((const float4*)gpE)[3];  // slice 0
  float4 cO0 = ((const float4*)gpO)[0], cO1 = ((const float4*)gpO)[1];
  float4 cO2 = ((const float4*)gpO)[2], cO3 = ((const float4*)gpO)[3];  // slice 1
  gpE += 16384; gpO += 16384;                     // -> slices 2, 3

#define CPAIR(CV, K) (((const f32x2*)&(CV))[(K)])

#define ROTE(E, CP) { \
    const int rF = ((E) - PHI) & 7, rS = ((E) + PHI) & 7; \
    const f32x2 cp_ = (CP); \
    const f32x2 t_ = pk_smul(cp_, SS[rS]); \
    const f32x2 u_ = pk_smul(cp_, FF[rF]); \
    FF[rF] = pk_cfma(cp_, FF[rF], t_); \
    SS[rS] = pk_cfma_neg(cp_, SS[rS], u_); }

  // Boundary logic is round-3's verified h-exchange, reg-phase period 8:
  // h0.l0: pos0 stationary (St) + pos2047->pos1 wrap (So into FF[pT]);
  // h0.l63 -> exF -> h1.l0 (F crossing up); h1.l0 -> exS -> h0.l63 (S crossing down);
  // h1.l63: ladder-top fold F->S (Fo).
#define STEP(PHI_, C0, C1, C2, C3, GP) { \
    const int PHI = (PHI_); \
    const int PAR = PHI & 1; \
    const int pF = (7 - PHI) & 7, pT = (8 - PHI) & 7; \
    ROTE(0, CPAIR(C0, 0)) ROTE(1, CPAIR(C0, 1)) \
    ROTE(2, CPAIR(C1, 0)) ROTE(3, CPAIR(C1, 1)) \
    ROTE(4, CPAIR(C2, 0)) ROTE(5, CPAIR(C2, 1)) \
    ROTE(6, CPAIR(C3, 0)) ROTE(7, CPAIR(C3, 1)) \
    const f32x2 Fo = FF[pF], So = SS[PHI], St = FF[pT]; \
    f32x2 fi, sd; \
    fi.x = dppf<DPP_UP>(Fo.x); fi.y = dppf<DPP_UP>(Fo.y); \
    sd.x = dppf<DPP_DN>(So.x); sd.y = dppf<DPP_DN>(So.y); \
    if (h1) { if (l0)  exS[PAR] = So; } \
    else    { if (l63) exF[PAR] = Fo; } \
    C0 = ((const float4*)GP)[0]; C1 = ((const float4*)GP)[1]; \
    C2 = ((const float4*)GP)[2]; C3 = ((const float4*)GP)[3]; \
    GP += 16384;                                   /* prefetch slice t+2 */ \
    asm volatile("s_waitcnt lgkmcnt(0)" ::: "memory"); \
    __builtin_amdgcn_s_barrier(); \
    __builtin_amdgcn_sched_barrier(0); \
    f32x2 eF = {0.f, 0.f}, eS = {0.f, 0.f}; \
    if (h1) { if (l0)  eF = exF[PAR]; } \
    else    { if (l63) eS = exS[PAR]; } \
    if (h1) { \
      FF[pF]  = l0  ? eF : fi; \
      SS[PHI] = l63 ? Fo : sd; \
    } else { \
      FF[pF]  = l0  ? St : fi; \
      SS[PHI] = l63 ? eS : sd; \
      FF[pT]  = l0  ? So : FF[pT]; \
    } \
  }

#pragma unroll 1
  for (int it = 0; it < 255; ++it) {
    STEP(0, cE0, cE1, cE2, cE3, gpE)
    STEP(1, cO0, cO1, cO2, cO3, gpO)
    STEP(2, cE0, cE1, cE2, cE3, gpE)
    STEP(3, cO0, cO1, cO2, cO3, gpO)
    STEP(4, cE0, cE1, cE2, cE3, gpE)
    STEP(5, cO0, cO1, cO2, cO3, gpO)
    STEP(6, cE0, cE1, cE2, cE3, gpE)
    STEP(7, cO0, cO1, cO2, cO3, gpO)
  }
  // tail: t = 2040..2046 (prefetches reach pad slices 2047/2048, never consumed)
  STEP(0, cE0, cE1, cE2, cE3, gpE)
  STEP(1, cO0, cO1, cO2, cO3, gpO)
  STEP(2, cE0, cE1, cE2, cE3, gpE)
  STEP(3, cO0, cO1, cO2, cO3, gpO)
  STEP(4, cE0, cE1, cE2, cE3, gpE)
  STEP(5, cO0, cO1, cO2, cO3, gpO)
  STEP(6, cE0, cE1, cE2, cE3, gpE)

  // Readout at T=2047 (round-3 verified): F col 512h+8l+e in FF[(e+1)&7];
  // S col 2047-(512h+8l+e) in SS[(e-1)&7].
#pragma unroll
  for (int rr = 0; rr < 2; ++rr) {
    unsigned short* rowp = Ub + (size_t)(r0 + rr) * NN;
    unsigned int uf[4], us[4];
#pragma unroll
    for (int j = 0; j < 4; ++j) {
      const float a0 = rr ? FF[(2*j + 1) & 7].y : FF[(2*j + 1) & 7].x;
      const float a1 = rr ? FF[(2*j + 2) & 7].y : FF[(2*j + 2) & 7].x;
      const float b0 = rr ? SS[(6 - 2*j) & 7].y : SS[(6 - 2*j) & 7].x;
      const float b1 = rr ? SS[(5 - 2*j) & 7].y : SS[(5 - 2*j) & 7].x;
      uf[j] = (unsigned)f2bf(a0) | ((unsigned)f2bf(a1) << 16);
      us[j] = (unsigned)f2bf(b0) | ((unsigned)f2bf(b1) << 16);
    }
    *(uint4*)(rowp + 512 * h + 8 * lane)        = make_uint4(uf[0], uf[1], uf[2], uf[3]);
    *(uint4*)(rowp + 2040 - 512 * h - 8 * lane) = make_uint4(us[0], us[1], us[2], us[3]);
  }
}

// ---- kernel 4: C = A * B^T + bias.  A = x_bf16 [8192][2048], B = U_bf16 [2048][2048]
#define BM 128
#define BN 128
#define BK 32

__global__ __launch_bounds__(256) void gemm_kernel(
    const unsigned short* __restrict__ A, const unsigned short* __restrict__ B,
    const float* __restrict__ bias, float* __restrict__ C) {
  __shared__ unsigned short As[BM * BK];
  __shared__ unsigned short Bs[BN * BK];
  const int tid  = threadIdx.x;
  const int lane = tid & 63;
  const int wave = tid >> 6;
  const int bm = blockIdx.x, bn = blockIdx.y;
  const int wm = wave & 1, wn = wave >> 1;

  const int srow = wave * 16 + (lane >> 2);
  const int scol = (lane & 3) * 8;
  const unsigned short* Ag = A + (size_t)(bm * BM + srow) * NN + scol;
  const unsigned short* Bg = B + (size_t)(bn * BN + srow) * NN + scol;

  const int fm = lane & 15;
  const int kb = lane >> 4;

  f32x4 acc[4][4];
#pragma unroll
  for (int a_ = 0; a_ < 4; ++a_)
#pragma unroll
    for (int b_ = 0; b_ < 4; ++b_) acc[a_][b_] = (f32x4){0.f, 0.f, 0.f, 0.f};

  for (int kt = 0; kt < NN / BK; ++kt) {
    const int k0 = kt * BK;
#pragma unroll
    for (int it = 0; it < 2; ++it) {
      gload_lds16(Ag + (size_t)(it * 64) * NN + k0, &As[wave * 512 + it * 2048]);
      gload_lds16(Bg + (size_t)(it * 64) * NN + k0, &Bs[wave * 512 + it * 2048]);
    }
    __syncthreads();

    bf16x8 af[4], bfr[4];
#pragma unroll
    for (int a_ = 0; a_ < 4; ++a_)
      af[a_] = *(const bf16x8*)&As[(wm * 64 + a_ * 16 + fm) * BK + kb * 8];
#pragma unroll
    for (int b_ = 0; b_ < 4; ++b_)
      bfr[b_] = *(const bf16x8*)&Bs[(wn * 64 + b_ * 16 + fm) * BK + kb * 8];
#pragma unroll
    for (int a_ = 0; a_ < 4; ++a_)
#pragma unroll
      for (int b_ = 0; b_ < 4; ++b_)
        acc[a_][b_] = __builtin_amdgcn_mfma_f32_16x16x32_bf16(af[a_], bfr[b_], acc[a_][b_], 0, 0, 0);
    __syncthreads();
  }

  const int row_in = (lane >> 4) * 4;
#pragma unroll
  for (int a_ = 0; a_ < 4; ++a_) {
#pragma unroll
    for (int b_ = 0; b_ < 4; ++b_) {
      int gn = bn * BN + wn * 64 + b_ * 16 + fm;
      float bv = bias[gn];
#pragma unroll
      for (int v = 0; v < 4; ++v) {
        int gm = bm * BM + wm * 64 + a_ * 16 + row_in + v;
        C[(size_t)gm * NN + gn] = acc[a_][b_][v] + bv;
      }
    }
  }
}

extern "C" void kernel_launch(void* const* d_in, const int* in_sizes, int n_in,
                              void* d_out, int out_size, void* d_ws, size_t ws_size,
                              hipStream_t stream) {
  const float* x      = (const float*)d_in[0];
  const float* angles = (const float*)d_in[1];
  const float* bias   = (const float*)d_in[2];
  float* out = (float*)d_out;

  char* ws = (char*)d_ws;
  char*           cs = ws;                                 // 2049 slices * 8KB = 16,785,408 B (2047 real + 2 pad)
  unsigned short* xb = (unsigned short*)(ws + 16785408);   // 33,554,432 B
  unsigned short* Ub = (unsigned short*)(ws + 50339840);   //  8,388,608 B
  // total 58,728,448 B

  prep_kernel<<<dim3(8188), dim3(256), 0, stream>>>(angles, (float2*)cs);
  cvt_kernel<<<dim3(16384), dim3(256), 0, stream>>>((const float4*)x, (ushort4*)xb,
                                                    MROWS * NN / 4);
  build_kernel<<<dim3(1024), dim3(128), 0, stream>>>(cs, Ub);
  gemm_kernel<<<dim3(MROWS / BM, NN / BN), dim3(256), 0, stream>>>(xb, Ub, bias, out);
}

// Round 11
// 931.182 us; speedup vs baseline: 1.1128x; 1.1128x over previous
//
#include <hip/hip_runtime.h>
#include <hip/hip_bf16.h>

#define NN      2048
#define NSTEPS  2047
#define NPAIRS  1024
#define MROWS   8192

typedef __attribute__((ext_vector_type(8))) __bf16 bf16x8;
typedef __attribute__((ext_vector_type(4))) float  f32x4;
typedef __attribute__((ext_vector_type(2))) float  f32x2;

__device__ __forceinline__ unsigned short f2bf(float f) {
  unsigned int u = __float_as_uint(f);
  u += 0x7fffu + ((u >> 16) & 1u);   // RNE
  return (unsigned short)(u >> 16);
}

__device__ __forceinline__ void gload_lds16(const void* g, void* l) {
  __builtin_amdgcn_global_load_lds((const __attribute__((address_space(1))) void*)g,
                                   (__attribute__((address_space(3))) void*)l, 16, 0, 0);
}

// DPP wave-wide lane shifts (VALU pipe, no LDS). Verified rounds 6-10.
template<int CTRL>
__device__ __forceinline__ float dppf(float v) {
  return __int_as_float(__builtin_amdgcn_update_dpp(
      __float_as_int(v), __float_as_int(v), CTRL, 0xf, 0xf, false));
}
#define DPP_UP 0x138   // wave_shr1: dst[i] = src[i-1]  (shfl_up 1)
#define DPP_DN 0x130   // wave_shl1: dst[i] = src[i+1]  (shfl_down 1)

// Packed fp32 math with op_sel broadcast from a (c,s) register pair. Verified rounds 7-10.
__device__ __forceinline__ f32x2 pk_smul(f32x2 cs, f32x2 v) {
  f32x2 d;
  asm("v_pk_mul_f32 %0, %1, %2 op_sel:[1,0] op_sel_hi:[1,1]"
      : "=v"(d) : "v"(cs), "v"(v));
  return d;
}
__device__ __forceinline__ f32x2 pk_cfma(f32x2 cs, f32x2 v, f32x2 a) {
  f32x2 d;
  asm("v_pk_fma_f32 %0, %1, %2, %3 op_sel:[0,0,0] op_sel_hi:[0,1,1]"
      : "=v"(d) : "v"(cs), "v"(v), "v"(a));
  return d;
}
__device__ __forceinline__ f32x2 pk_cfma_neg(f32x2 cs, f32x2 v, f32x2 a) {
  f32x2 d;
  asm("v_pk_fma_f32 %0, %1, %2, %3 op_sel:[0,0,0] op_sel_hi:[0,1,1] neg_lo:[0,0,1] neg_hi:[0,0,1]"
      : "=v"(d) : "v"(cs), "v"(v), "v"(a));
  return d;
}

// ---- kernel 1: angles -> (cos,sin) table, layout cs[step][pair] (8 KB/step slice)
__global__ __launch_bounds__(256) void prep_kernel(
    const float* __restrict__ angles, float2* __restrict__ cs) {
  int idx = blockIdx.x * 256 + threadIdx.x;
  if (idx >= NSTEPS * NPAIRS) return;
  float s, c;
  sincosf(angles[idx], &s, &c);
  cs[idx] = make_float2(c, s);
}

// ---- kernel 2: x fp32 -> bf16 (vectorized)
__global__ __launch_bounds__(256) void cvt_kernel(
    const float4* __restrict__ x, ushort4* __restrict__ xb, int n4) {
  int idx = blockIdx.x * 256 + threadIdx.x;
  if (idx >= n4) return;
  float4 v = x[idx];
  ushort4 o;
  o.x = f2bf(v.x); o.y = f2bf(v.y); o.z = f2bf(v.z); o.w = f2bf(v.w);
  xb[idx] = o;
}

// ---- kernel 3: register-systolic build of U (position space, static pairing).
// EXACT round-8 structure (8-wave WG = q-quarter x g-rowgroup, R=2 rows, P=4
// pairs/lane, 4096 waves = 4/SIMD) with plumbing cuts:
//  (1) unconditional per-lane-slot LDS exchange (no exec-mask juggling; readers
//      do broadcast reads of the single boundary slot, selected by cndmask);
//  (2) wave-uniform SGPR-base cs loads (readfirstlane) -> SALU address inc;
//  (3) flattened boundary selects on always-read (clamped) cross values.
__global__ __launch_bounds__(512, 4) void build_kernel(
    const char* __restrict__ csb, unsigned short* __restrict__ Ub) {
  __shared__ f32x2 exFb[2][8][64];   // [parity][wave][lane] : 8 KB
  __shared__ f32x2 exSb[2][8][64];   // 8 KB

  const int tid  = threadIdx.x;
  const int lane = tid & 63;
  const int wv   = tid >> 6;
  const int q    = wv & 3;                 // pair-quarter
  const int g    = wv >> 2;                // row-group
  const int r0   = blockIdx.x * 4 + 2 * g; // rows r0, r0+1
  const bool l0 = (lane == 0), l63 = (lane == 63);
  const bool q0 = (q == 0), q3 = (q == 3);

  // clamped boundary-source waves (junk for q0/q3, selected away)
  const int wvF = q0 ? wv : wv - 1;        // F crossing: from quarter q-1, lane 63
  const int wvS = q3 ? wv : wv + 1;        // S crossing: from quarter q+1, lane 0

  // state: elem e <-> pair p = 256q + 4*lane + e; .x = row r0, .y = row r0+1
  f32x2 FF[4], SS[4];
#pragma unroll
  for (int e = 0; e < 4; ++e) {
    const int p = 256 * q + 4 * lane + e, m = 2047 - p;
    FF[e] = (f32x2){(p == r0) ? 1.f : 0.f, (p == r0 + 1) ? 1.f : 0.f};
    SS[e] = (f32x2){(m == r0) ? 1.f : 0.f, (m == r0 + 1) ? 1.f : 0.f};
  }

  // cs: lane's 4 pairs = 32B at slice_base + 2048q + 32*lane.
  // SGPR base (readfirstlane) + VGPR lane offset + uniform running byte offset.
  const int qu = __builtin_amdgcn_readfirstlane(q);
  const char* csq = csb + 2048 * qu;       // wave-uniform
  const int voff = 32 * lane;
  int soE = 0, soO = 8192;
  float4 cvE0 = ((const float4*)(csq + soE + voff))[0];
  float4 cvE1 = ((const float4*)(csq + soE + voff))[1];   // slice 0
  float4 cvO0 = ((const float4*)(csq + soO + voff))[0];
  float4 cvO1 = ((const float4*)(csq + soO + voff))[1];   // slice 1
  soE = 16384; soO = 24576;                // -> slices 2, 3

#define CPAIR(CV, K) (((const f32x2*)&(CV))[(K)])

#define ROT1(E, CP) { \
    const int rF = ((E) - PHI) & 3, rS = ((E) + PHI) & 3; \
    const f32x2 cp_ = (CP); \
    const f32x2 t_ = pk_smul(cp_, SS[rS]); \
    const f32x2 u_ = pk_smul(cp_, FF[rF]); \
    FF[rF] = pk_cfma(cp_, FF[rF], t_); \
    SS[rS] = pk_cfma_neg(cp_, SS[rS], u_); }

#define STEP(PHI_, C0, C1, SO) { \
    const int PHI = (PHI_); \
    const int PAR = PHI & 1; \
    const int pF = (3 - PHI) & 3, pT = (4 - PHI) & 3; \
    ROT1(0, CPAIR(C0, 0)) ROT1(1, CPAIR(C0, 1)) \
    ROT1(2, CPAIR(C1, 0)) ROT1(3, CPAIR(C1, 1)) \
    const f32x2 Fo = FF[pF], So = SS[PHI], St = FF[pT]; \
    f32x2 fi, sd; \
    fi.x = dppf<DPP_UP>(Fo.x); fi.y = dppf<DPP_UP>(Fo.y); \
    sd.x = dppf<DPP_DN>(So.x); sd.y = dppf<DPP_DN>(So.y); \
    exFb[PAR][wv][lane] = Fo;                       /* unconditional ds_write */ \
    exSb[PAR][wv][lane] = So; \
    C0 = ((const float4*)(csq + SO + voff))[0];     /* prefetch slice t+2 */ \
    C1 = ((const float4*)(csq + SO + voff))[1]; \
    SO += 16384; \
    asm volatile("s_waitcnt lgkmcnt(0)" ::: "memory"); \
    __builtin_amdgcn_s_barrier(); \
    __builtin_amdgcn_sched_barrier(0); \
    const f32x2 crF = exFb[PAR][wvF][63];           /* broadcast reads */ \
    const f32x2 crS = exSb[PAR][wvS][0]; \
    asm volatile("s_waitcnt lgkmcnt(0)" ::: "memory"); \
    __builtin_amdgcn_sched_barrier(0); \
    const f32x2 xF = q0 ? St : crF; \
    const f32x2 xS = q3 ? Fo : crS; \
    FF[pF]  = l0  ? xF : fi; \
    SS[PHI] = l63 ? xS : sd; \
    if (q0) { FF[pT] = l0 ? So : FF[pT]; } \
  }

#pragma unroll 1
  for (int it = 0; it < 511; ++it) {
    STEP(0, cvE0, cvE1, soE)
    STEP(1, cvO0, cvO1, soO)
    STEP(2, cvE0, cvE1, soE)
    STEP(3, cvO0, cvO1, soO)
  }
  // tail: t = 2044, 2045, 2046 (prefetches reach pad slices 2047/2048, never consumed)
  STEP(0, cvE0, cvE1, soE)
  STEP(1, cvO0, cvO1, soO)
  STEP(2, cvE0, cvE1, soE)

  // Readout at T=2047 (cycle closed; 2047 mod 4 = 3) — round-5/8 verified mapping:
  // F elem e in reg (e+1)&3, col 256q+4l+e; S elem e in reg (e-1)&3, col 2047-(256q+4l+e)
  const int cf  = 256 * q + 4 * lane;
  const int cs_ = 2044 - cf;
#pragma unroll
  for (int rr = 0; rr < 2; ++rr) {
    unsigned short* rp = Ub + (size_t)(r0 + rr) * NN;
    const float f1 = rr ? FF[1].y : FF[1].x, f2 = rr ? FF[2].y : FF[2].x;
    const float f3 = rr ? FF[3].y : FF[3].x, f0 = rr ? FF[0].y : FF[0].x;
    const float s2 = rr ? SS[2].y : SS[2].x, s1 = rr ? SS[1].y : SS[1].x;
    const float s0 = rr ? SS[0].y : SS[0].x, s3 = rr ? SS[3].y : SS[3].x;
    const unsigned uf0 = (unsigned)f2bf(f1) | ((unsigned)f2bf(f2) << 16);
    const unsigned uf1 = (unsigned)f2bf(f3) | ((unsigned)f2bf(f0) << 16);
    const unsigned us0 = (unsigned)f2bf(s2) | ((unsigned)f2bf(s1) << 16);
    const unsigned us1 = (unsigned)f2bf(s0) | ((unsigned)f2bf(s3) << 16);
    *(uint2*)(rp + cf)  = make_uint2(uf0, uf1);
    *(uint2*)(rp + cs_) = make_uint2(us0, us1);
  }
}

// ---- kernel 4: C = A * B^T + bias.  A = x_bf16 [8192][2048], B = U_bf16 [2048][2048]
#define BM 128
#define BN 128
#define BK 32

__global__ __launch_bounds__(256) void gemm_kernel(
    const unsigned short* __restrict__ A, const unsigned short* __restrict__ B,
    const float* __restrict__ bias, float* __restrict__ C) {
  __shared__ unsigned short As[BM * BK];
  __shared__ unsigned short Bs[BN * BK];
  const int tid  = threadIdx.x;
  const int lane = tid & 63;
  const int wave = tid >> 6;
  const int bm = blockIdx.x, bn = blockIdx.y;
  const int wm = wave & 1, wn = wave >> 1;

  const int srow = wave * 16 + (lane >> 2);
  const int scol = (lane & 3) * 8;
  const unsigned short* Ag = A + (size_t)(bm * BM + srow) * NN + scol;
  const unsigned short* Bg = B + (size_t)(bn * BN + srow) * NN + scol;

  const int fm = lane & 15;
  const int kb = lane >> 4;

  f32x4 acc[4][4];
#pragma unroll
  for (int a_ = 0; a_ < 4; ++a_)
#pragma unroll
    for (int b_ = 0; b_ < 4; ++b_) acc[a_][b_] = (f32x4){0.f, 0.f, 0.f, 0.f};

  for (int kt = 0; kt < NN / BK; ++kt) {
    const int k0 = kt * BK;
#pragma unroll
    for (int it = 0; it < 2; ++it) {
      gload_lds16(Ag + (size_t)(it * 64) * NN + k0, &As[wave * 512 + it * 2048]);
      gload_lds16(Bg + (size_t)(it * 64) * NN + k0, &Bs[wave * 512 + it * 2048]);
    }
    __syncthreads();

    bf16x8 af[4], bfr[4];
#pragma unroll
    for (int a_ = 0; a_ < 4; ++a_)
      af[a_] = *(const bf16x8*)&As[(wm * 64 + a_ * 16 + fm) * BK + kb * 8];
#pragma unroll
    for (int b_ = 0; b_ < 4; ++b_)
      bfr[b_] = *(const bf16x8*)&Bs[(wn * 64 + b_ * 16 + fm) * BK + kb * 8];
#pragma unroll
    for (int a_ = 0; a_ < 4; ++a_)
#pragma unroll
      for (int b_ = 0; b_ < 4; ++b_)
        acc[a_][b_] = __builtin_amdgcn_mfma_f32_16x16x32_bf16(af[a_], bfr[b_], acc[a_][b_], 0, 0, 0);
    __syncthreads();
  }

  const int row_in = (lane >> 4) * 4;
#pragma unroll
  for (int a_ = 0; a_ < 4; ++a_) {
#pragma unroll
    for (int b_ = 0; b_ < 4; ++b_) {
      int gn = bn * BN + wn * 64 + b_ * 16 + fm;
      float bv = bias[gn];
#pragma unroll
      for (int v = 0; v < 4; ++v) {
        int gm = bm * BM + wm * 64 + a_ * 16 + row_in + v;
        C[(size_t)gm * NN + gn] = acc[a_][b_][v] + bv;
      }
    }
  }
}

extern "C" void kernel_launch(void* const* d_in, const int* in_sizes, int n_in,
                              void* d_out, int out_size, void* d_ws, size_t ws_size,
                              hipStream_t stream) {
  const float* x      = (const float*)d_in[0];
  const float* angles = (const float*)d_in[1];
  const float* bias   = (const float*)d_in[2];
  float* out = (float*)d_out;

  char* ws = (char*)d_ws;
  char*           cs = ws;                                 // 2049 slices * 8KB = 16,785,408 B (2047 real + 2 pad)
  unsigned short* xb = (unsigned short*)(ws + 16785408);   // 33,554,432 B
  unsigned short* Ub = (unsigned short*)(ws + 50339840);   //  8,388,608 B
  // total 58,728,448 B

  prep_kernel<<<dim3(8188), dim3(256), 0, stream>>>(angles, (float2*)cs);
  cvt_kernel<<<dim3(16384), dim3(256), 0, stream>>>((const float4*)x, (ushort4*)xb,
                                                    MROWS * NN / 4);
  build_kernel<<<dim3(512), dim3(512), 0, stream>>>(cs, Ub);
  gemm_kernel<<<dim3(MROWS / BM, NN / BN), dim3(256), 0, stream>>>(xb, Ub, bias, out);
}